// Round 3
// baseline (409.586 us; speedup 1.0000x reference)
//
#include <hip/hip_runtime.h>
#include <hip/hip_bf16.h>

typedef __attribute__((ext_vector_type(4))) float floatx4;
typedef __attribute__((ext_vector_type(8))) short shortx8;

#define HW   1024
#define C    128
#define EPS  1e-8f

// Kernel 1: normalize over channel dim + transpose to fnT[view][p][c] (bf16)
// x: [32 views][128 c][1024 p] fp32.  fnT: [32][1024][128] bf16 (8 MB in d_ws)
__global__ __launch_bounds__(64) void norm_transpose(const float* __restrict__ x,
                                                     __hip_bfloat16* __restrict__ fnT) {
    int g = blockIdx.x * 64 + threadIdx.x;    // g in [0, 32*1024)
    int v = g >> 10;
    int p = g & 1023;
    const float* xv = x + (size_t)v * (C * HW) + p;
    float s = 0.f;
#pragma unroll
    for (int c = 0; c < C; ++c) {
        float val = xv[(size_t)c * HW];      // coalesced: lanes = consecutive p
        s += val * val;
    }
    float scale = 1.0f / (sqrtf(s) + EPS);
    __hip_bfloat16* dst = fnT + (size_t)g * C;
#pragma unroll
    for (int c0 = 0; c0 < C; c0 += 8) {
        shortx8 pack;
#pragma unroll
        for (int u = 0; u < 8; ++u) {
            __hip_bfloat16 h = __float2bfloat16(xv[(size_t)(c0 + u) * HW] * scale);
            pack[u] = *(short*)&h;
        }
        *(shortx8*)(dst + c0) = pack;        // 16B store per thread
    }
}

// Kernel 2: 96 GEMMs C[p,q] = sum_c fnT[vA][p][c] * fnT[vB][q][c]
//
// Round-3 structure: 64x64 output tiles, 32 KB LDS/block -> 4 blocks/CU
// (16 waves/CU). The write stream (402 MB, the roofline term) needs stores
// issuing continuously; at 2 blocks/CU the stage->barrier->compute->barrier
// phases left the store pipe idle most of each block's lifetime. 4 staggered
// blocks/CU keep it fed. LDS-bounce epilogue dropped (measured neutral in
// round 1) -- direct NT scalar stores from acc.
//
// Staging: one-shot K=128 via global_load_lds(16B), XOR-chunk swizzle
// (LDS slot (row,c) holds global chunk (row, c ^ (row&15)); row stride 256 B
// is bank-aligned so unswizzled b128 reads would be ~8-way conflicted;
// swizzled reads are 2-way = free, measured 0 conflicts).
//
// XCD-chunked grid swizzle: 24576 blocks = 8 XCDs x 3072; each XCD walks
// one g's 512 KB fnT slab at a time -> reads stay L2-local (+10 us measured
// in round 2).
__global__ __launch_bounds__(256, 4) void corr_gemm(const __hip_bfloat16* __restrict__ fnT,
                                                    float* __restrict__ out) {
    __shared__ short Atile[64 * 128];   // 16 KB: rows p0..p0+63, 128 c bf16
    __shared__ short Btile[64 * 128];   // 16 KB: rows q0..q0+63

    // --- XCD-chunked swizzle (24576 = 8 x 3072, bijective) ---
    int bid = blockIdx.x;
    int swz = (bid & 7) * 3072 + (bid >> 3);
    int g   = swz >> 8;              // 256 tiles per g
    int rem = swz & 255;
    int p0  = (rem >> 4) << 6;       // (rem/16)*64
    int q0  = (rem & 15) << 6;       // (rem%16)*64

    int b = g / 12;
    int r = g % 12;
    int i = r / 3;
    int k = r % 3;
    int j = k + (k >= i);        // jj[i][k]
    int vA = b * 4 + j;          // provides p (rows)
    int vB = b * 4 + i;          // provides q (cols)

    int lane = threadIdx.x & 63;
    int wave = threadIdx.x >> 6;

    // --- Stage: A/B tiles are contiguous 16 KB slabs of fnT ---
    const char* Ag = (const char*)(fnT + ((size_t)vA * HW + p0) * C);
    const char* Bg = (const char*)(fnT + ((size_t)vB * HW + q0) * C);
    char* Alds = (char*)&Atile[0];
    char* Blds = (char*)&Btile[0];
#pragma unroll
    for (int t = 0; t < 4; ++t) {
        int s = (wave * 4 + t) * 64 + lane;          // chunk slot 0..1023
        int row = s >> 4;
        int c16 = s & 15;
        int goff = (row * 16 + (c16 ^ (row & 15))) * 16;
        int loff = (wave * 4 + t) * 1024;            // wave-uniform LDS base
        __builtin_amdgcn_global_load_lds(
            (const __attribute__((address_space(1))) void*)(Ag + goff),
            (__attribute__((address_space(3))) void*)(Alds + loff), 16, 0, 0);
        __builtin_amdgcn_global_load_lds(
            (const __attribute__((address_space(1))) void*)(Bg + goff),
            (__attribute__((address_space(3))) void*)(Blds + loff), 16, 0, 0);
    }
    __syncthreads();   // compiler emits vmcnt(0) drain before s_barrier

    // --- Compute: wave -> 32x32 subtile, 2x2 grid of 16x16x32 MFMA ---
    int wp = (wave >> 1) * 32;
    int wq = (wave & 1) * 32;
    int lr   = lane & 15;
    int quad = lane >> 4;

    const char* Ab = (const char*)&Atile[0] + (size_t)(wp + lr) * 256;
    const char* Bb = (const char*)&Btile[0] + (size_t)(wq + lr) * 256;

    floatx4 acc[2][2] = {};

#pragma unroll
    for (int kk = 0; kk < 4; ++kk) {                 // K = 128 in 4 steps of 32
        int co = ((kk * 4 + quad) ^ lr) * 16;        // swizzled chunk (row&15 == lr)
        shortx8 a[2], bfr[2];
#pragma unroll
        for (int t = 0; t < 2; ++t) {
            a[t]   = *(const shortx8*)(Ab + t * 16 * 256 + co);
            bfr[t] = *(const shortx8*)(Bb + t * 16 * 256 + co);
        }
#pragma unroll
        for (int mt = 0; mt < 2; ++mt)
#pragma unroll
            for (int nt = 0; nt < 2; ++nt)
                acc[mt][nt] = __builtin_amdgcn_mfma_f32_16x16x32_bf16(a[mt], bfr[nt], acc[mt][nt], 0, 0, 0);
    }

    // --- Epilogue: direct NT stores. D layout: col=lane&15, row=quad*4+reg ---
    float* outg = out + (size_t)g * (HW * HW);
#pragma unroll
    for (int mt = 0; mt < 2; ++mt) {
#pragma unroll
        for (int rr = 0; rr < 4; ++rr) {
            int row = p0 + wp + mt * 16 + quad * 4 + rr;
            float* orow = outg + (size_t)row * HW + q0 + wq + lr;
#pragma unroll
            for (int nt = 0; nt < 2; ++nt)
                __builtin_nontemporal_store(acc[mt][nt][rr], orow + nt * 16);
        }
    }
}

extern "C" void kernel_launch(void* const* d_in, const int* in_sizes, int n_in,
                              void* d_out, int out_size, void* d_ws, size_t ws_size,
                              hipStream_t stream) {
    const float* x = (const float*)d_in[0];
    float* out = (float*)d_out;
    __hip_bfloat16* fnT = (__hip_bfloat16*)d_ws;   // 32*1024*128*2 = 8 MB

    norm_transpose<<<dim3(32 * 1024 / 64), 64, 0, stream>>>(x, fnT);
    corr_gemm<<<dim3(24576), 256, 0, stream>>>(fnT, out);
}